// Round 14
// baseline (147.092 us; speedup 1.0000x reference)
//
#include <hip/hip_runtime.h>
#include <hip/hip_bf16.h>
#include <math.h>

#define T_DIM 1024
#define B_DIM 32
#define DIMF 512
#define DIMH 512
#define DIMS 1024
#define DIMW 512

typedef __attribute__((ext_vector_type(8))) short short8;
typedef __attribute__((ext_vector_type(4))) float f32x4;

__device__ __forceinline__ unsigned f2bf1(float x) {
    unsigned a = __float_as_uint(x);
    return (a + 0x7FFFu + ((a >> 16) & 1u)) >> 16;
}
__device__ __forceinline__ unsigned f2bf2(float lo, float hi) {
    return f2bf1(lo) | (f2bf1(hi) << 16);
}
__device__ __forceinline__ float fast_tanh(float x) {
    return 1.f - __fdividef(2.f, 1.f + __expf(x + x));
}
__device__ __forceinline__ unsigned short bf1(float x) {
    __hip_bfloat16 b = __float2bfloat16(x);
    return *reinterpret_cast<unsigned short*>(&b);
}
__device__ __forceinline__ short8 pack8(float4 a, float4 c) {
    union { unsigned short us[8]; short8 s; } u;
    u.us[0] = bf1(a.x); u.us[1] = bf1(a.y); u.us[2] = bf1(a.z); u.us[3] = bf1(a.w);
    u.us[4] = bf1(c.x); u.us[5] = bf1(c.y); u.us[6] = bf1(c.z); u.us[7] = bf1(c.w);
    return u.s;
}

// async global->LDS, 16B/lane; LDS dest wave-uniform, global src per-lane
__device__ __forceinline__ void gl16(const unsigned short* g, unsigned short* l) {
    __builtin_amdgcn_global_load_lds(
        (const __attribute__((address_space(1))) unsigned int*)g,
        (__attribute__((address_space(3))) unsigned int*)l, 16, 0, 0);
}
__device__ __forceinline__ void gl16f(const float* g, float* l) {
    __builtin_amdgcn_global_load_lds(
        (const __attribute__((address_space(1))) unsigned int*)g,
        (__attribute__((address_space(3))) unsigned int*)l, 16, 0, 0);
}

// ================= merged prep kernel (r12-verified) =================
__global__ void __launch_bounds__(256) k_prep_all(
    const float* __restrict__ F, const float* __restrict__ Uw,
    const float* __restrict__ Vw, const float* __restrict__ a_prev,
    const float* __restrict__ s_prev, const float* __restrict__ Ww,
    const float* __restrict__ Vb, const float* __restrict__ h,
    unsigned short* __restrict__ GT, unsigned short* __restrict__ VwT,
    unsigned short* __restrict__ P, float* __restrict__ SWp,
    unsigned short* __restrict__ hB, int nPack) {
    __shared__ float sh[8192];
    const int bz = blockIdx.x;
    const int tid = threadIdx.x;

    if (bz < nPack) {
        for (unsigned i = bz * 256 + tid; i < 32768u * 64; i += (unsigned)nPack * 256) {
            const int r = i >> 6, c8 = (i & 63) * 8;
            const int bb = r >> 10, t = r & 1023;
            const float* src = h + ((size_t)(t * 32 + bb)) * 512 + c8;
            const float4 v0 = *(const float4*)(src);
            const float4 v1 = *(const float4*)(src + 4);
            union { unsigned short us[8]; uint4 u4; } o;
            o.us[0] = bf1(v0.x); o.us[1] = bf1(v0.y);
            o.us[2] = bf1(v0.z); o.us[3] = bf1(v0.w);
            o.us[4] = bf1(v1.x); o.us[5] = bf1(v1.y);
            o.us[6] = bf1(v1.z); o.us[7] = bf1(v1.w);
            *(uint4*)(hB + (size_t)r * 512 + c8) = o.u4;
        }
        return;
    }
    const int bz2 = bz - nPack;
    if (bz2 < 512) {
        const int rt = bz2 & 63, ct = bz2 >> 6;
        const int r0g = rt * 16;
        const float4* Fv = (const float4*)(F + (size_t)r0g * DIMF);
        float4* shv = (float4*)sh;
        for (int i = tid; i < 16 * DIMF / 4; i += 256) shv[i] = Fv[i];
        __syncthreads();
        const int c = ct * 64 + (tid & 63);
        const int r0 = (tid >> 6) * 4;
        float acc[4] = {0.f, 0.f, 0.f, 0.f};
        for (int k = 0; k < DIMF; ++k) {
            const float bv = Uw[(size_t)k * DIMW + c];
#pragma unroll
            for (int j = 0; j < 4; ++j)
                acc[j] = fmaf(sh[(r0 + j) * DIMF + k], bv, acc[j]);
        }
        uint2 o;
        o.x = f2bf2(acc[0], acc[1]);
        o.y = f2bf2(acc[2], acc[3]);
        *(uint2*)(GT + (size_t)c * T_DIM + r0g + r0) = o;
        return;
    }
    const int bz3 = bz2 - 512;
    if (bz3 < 512) {
        if (bz3 < 256) {
            const int k0 = (bz3 >> 4) * 32, n0 = (bz3 & 15) * 32;
            const int x = tid & 31, y = tid >> 5;
#pragma unroll
            for (int i = 0; i < 4; ++i)
                sh[(y + 8 * i) * 33 + x] = Vw[(size_t)(k0 + y + 8 * i) * DIMW + n0 + x];
            __syncthreads();
#pragma unroll
            for (int i = 0; i < 4; ++i) {
                const int n = n0 + y + 8 * i;
                VwT[(size_t)n * DIMH + k0 + x] = (unsigned short)f2bf1(sh[x * 33 + y + 8 * i]);
            }
        } else {
            const int bs = bz3 - 256;
            const int b = bs >> 3, s = bs & 7;
            for (int i = tid; i < 2048; i += 256) {
                const int j = i + s;
                float v = 0.f;
                if (j >= 512 && j < 1536) v = a_prev[(size_t)b * T_DIM + j - 512];
                P[(size_t)bs * 2048 + i] = (unsigned short)f2bf1(v);
            }
        }
        return;
    }
    {
        const int bz4 = bz3 - 512;
        const int c0 = (bz4 & 15) * 32, q = bz4 >> 4;
        float (*shb)[256] = (float(*)[256])sh;
        for (int i = tid; i < 32 * 64; i += 256) {
            const int r = i >> 6, c4 = (i & 63) * 4;
            *(float4*)&shb[r][c4] = *(const float4*)(s_prev + (size_t)r * DIMS + q * 256 + c4);
        }
        __syncthreads();
        const int c  = c0 + (tid & 31);
        const int bg = tid >> 5;
        float acc[4];
#pragma unroll
        for (int j = 0; j < 4; ++j) acc[j] = (q == 0) ? Vb[c] : 0.f;
        const float* W = Ww + (size_t)q * 256 * DIMW;
        for (int k = 0; k < 256; ++k) {
            const float w = W[(size_t)k * DIMW + c];
#pragma unroll
            for (int j = 0; j < 4; ++j)
                acc[j] = fmaf(shb[bg + 8 * j][k], w, acc[j]);
        }
#pragma unroll
        for (int j = 0; j < 4; ++j)
            SWp[((size_t)q * B_DIM + bg + 8 * j) * DIMW + c] = acc[j];
    }
}

// ============ pipelined k_main (order-pinned): A->regs 1-ahead, B->LDS ring-3 2-ahead ============
// grid 1024 (XCD-swizzled), 256 threads (4 waves 2x2), tile 128x128, BK=64
__global__ void __launch_bounds__(256) k_main_pipe(
    const unsigned short* __restrict__ hB, const unsigned short* __restrict__ VwT,
    const unsigned short* __restrict__ GT, const unsigned short* __restrict__ P,
    const float* __restrict__ SWp, const float* __restrict__ ww,
    float* __restrict__ ep) {
    __shared__ unsigned short Bs[3][128 * 64];   // 48 KB ring

    const int bid = blockIdx.x;
    const int wg  = (bid & 7) * 128 + (bid >> 3);   // bijective: 1024 % 8 == 0
    const int x = wg & 3, yy = wg >> 2;
    const int w0 = x * 128;
    const int b  = yy >> 3;
    const int t0 = (yy & 7) * 128;

    const int tid  = threadIdx.x;
    const int lane = tid & 63;
    const int wv   = tid >> 6;
    const int wm = wv >> 1, wn = wv & 1;
    const int g = lane >> 4, r16 = lane & 15, g8 = g * 8;
    const int s7 = r16 & 7;

    f32x4 acc[4][4];
#pragma unroll
    for (int m = 0; m < 4; ++m)
#pragma unroll
        for (int n = 0; n < 4; ++n) acc[m][n] = (f32x4)0.f;

    const int kstart = max(0, t0 - 512);
    const int kend   = min(T_DIM - 1, t0 + 639);
    const int NS2    = (kend - kstart + 1) >> 6;    // even, 10..16
    const int NT     = 8 + NS2;                     // even, 18..24

    // ---- B staging sources (pre-swizzled, r12-verified): 4 gl16/wave/step ----
    const int rB = lane >> 3;                       // row-in-8 (= row&7)
    const int cB = ((lane & 7) ^ rB) * 8;
    const unsigned short* vS[4];
    const unsigned short* gS[4];
#pragma unroll
    for (int q = 0; q < 4; ++q) {
        vS[q] = VwT + (size_t)(w0 + wv * 32 + q * 8 + rB) * DIMH + cB;
        gS[q] = GT  + (size_t)(w0 + wv * 32 + q * 8 + rB) * T_DIM + kstart + cB;
    }

    // ---- A per-lane register sources ----
    const int trow0 = t0 + wm * 64 + r16;
    const unsigned short* hA[4];
#pragma unroll
    for (int m = 0; m < 4; ++m)
        hA[m] = hB + ((size_t)(b * 1024 + trow0 + m * 16)) * 512 + g8;
    const unsigned short* Pb = P + (size_t)b * 8 * 2048;
    const unsigned short* pA[4];
#pragma unroll
    for (int m = 0; m < 4; ++m) {
        const int trow = trow0 + m * 16;
        const int jb = kstart + g8 + 1024 - trow;   // in [1, 2040]
        const int sj = jb & 7;
        pA[m] = Pb + sj * 2048 + (jb - sj);
    }
    const bool zrow = (trow0 == 0);

#define FENCE() __builtin_amdgcn_sched_barrier(0)
#define STAGEB(u2, j)                                                        \
    {                                                                        \
        if ((u2) < 8) {                                                      \
            _Pragma("unroll")                                                \
            for (int q = 0; q < 4; ++q)                                      \
                gl16(vS[q] + (u2) * 64, &Bs[j][(wv * 32 + q * 8) * 64]);     \
        } else {                                                             \
            _Pragma("unroll")                                                \
            for (int q = 0; q < 4; ++q)                                      \
                gl16(gS[q] + ((u2) - 8) * 64, &Bs[j][(wv * 32 + q * 8) * 64]); \
        }                                                                    \
    }
#define LOADA(AF, u1)                                                        \
    {                                                                        \
        if ((u1) < 8) {                                                      \
            _Pragma("unroll")                                                \
            for (int m = 0; m < 4; ++m) {                                    \
                AF[m * 2]     = *(const short8*)(hA[m] + (u1) * 64);         \
                AF[m * 2 + 1] = *(const short8*)(hA[m] + (u1) * 64 + 32);    \
            }                                                                \
        } else {                                                             \
            _Pragma("unroll")                                                \
            for (int m = 0; m < 4; ++m) {                                    \
                AF[m * 2]     = *(const short8*)(pA[m] + ((u1) - 8) * 64);   \
                AF[m * 2 + 1] = *(const short8*)(pA[m] + ((u1) - 8) * 64 + 32); \
            }                                                                \
            if (zrow) { AF[0] = (short8)(short)0; AF[1] = (short8)(short)0; } \
        }                                                                    \
    }
// Pinned issue order per step: [STAGEB(u+2)] | [LOADA(u+1)] | [ds_read+MFMA] | vmcnt | barrier |
// Invariant: A(u) issued AFTER B(u+1) in step u-1, so the compiler's pre-MFMA wait on A(u)
// (in-order vmcnt) drains B(u+1) before this step's end barrier -> safe to read in step u+1.
#define STEP(AFc, AFn, u)                                                    \
    {                                                                        \
        int rc2 = rc + 2; if (rc2 >= 3) rc2 -= 3;                            \
        if ((u) + 2 < NT) STAGEB((u) + 2, rc2);                              \
        FENCE();                                                             \
        if ((u) + 1 < NT) LOADA(AFn, (u) + 1);                               \
        FENCE();                                                             \
        const unsigned short* Bc = &Bs[rc][0];                               \
        short8 bf0[4], bf1[4];                                               \
        _Pragma("unroll")                                                    \
        for (int n = 0; n < 4; ++n) {                                        \
            const int rowb = (wn * 64 + n * 16 + r16) * 64;                  \
            bf0[n] = *(const short8*)(Bc + rowb + ((g) ^ s7) * 8);           \
            bf1[n] = *(const short8*)(Bc + rowb + ((4 + g) ^ s7) * 8);       \
        }                                                                    \
        _Pragma("unroll")                                                    \
        for (int m = 0; m < 4; ++m)                                          \
            _Pragma("unroll")                                                \
            for (int n = 0; n < 4; ++n)                                      \
                acc[m][n] = __builtin_amdgcn_mfma_f32_16x16x32_bf16(         \
                    AFc[m * 2], bf0[n], acc[m][n], 0, 0, 0);                 \
        _Pragma("unroll")                                                    \
        for (int m = 0; m < 4; ++m)                                          \
            _Pragma("unroll")                                                \
            for (int n = 0; n < 4; ++n)                                      \
                acc[m][n] = __builtin_amdgcn_mfma_f32_16x16x32_bf16(         \
                    AFc[m * 2 + 1], bf1[n], acc[m][n], 0, 0, 0);             \
        FENCE();                                                             \
        asm volatile("s_waitcnt vmcnt(12)" ::: "memory");                    \
        __builtin_amdgcn_s_barrier();                                        \
        FENCE();                                                             \
        rc = rc + 1; if (rc >= 3) rc -= 3;                                   \
    }

    short8 afP[8], afQ[8];
    // ---- prologue (pinned): B(0); B(1); A(0); drain oldest 4 = B(0); barrier ----
    STAGEB(0, 0);
    FENCE();
    STAGEB(1, 1);
    FENCE();
    LOADA(afP, 0);
    FENCE();
    asm volatile("s_waitcnt vmcnt(12)" ::: "memory");
    __builtin_amdgcn_s_barrier();
    FENCE();

    int rc = 0;
    for (int u = 0; u < NT; u += 2) {
        STEP(afP, afQ, u);
        STEP(afQ, afP, u + 1);
    }

#undef STAGEB
#undef LOADA
#undef STEP
#undef FENCE

    // ---- epilogue (r12-verified) ----
    float swv[4], wwv[4];
#pragma unroll
    for (int n = 0; n < 4; ++n) {
        const int w = w0 + wn * 64 + n * 16 + r16;
        float sv = 0.f;
#pragma unroll
        for (int q = 0; q < 4; ++q)
            sv += SWp[((size_t)q * B_DIM + b) * DIMW + w];
        swv[n] = sv;
        wwv[n] = ww[w];
    }
#pragma unroll
    for (int m = 0; m < 4; ++m) {
#pragma unroll
        for (int reg = 0; reg < 4; ++reg) {
            float s = 0.f;
#pragma unroll
            for (int n = 0; n < 4; ++n)
                s = fmaf(fast_tanh(acc[m][n][reg] + swv[n]), wwv[n], s);
            s += __shfl_xor(s, 1, 64);
            s += __shfl_xor(s, 2, 64);
            s += __shfl_xor(s, 4, 64);
            s += __shfl_xor(s, 8, 64);
            if (r16 == 0) {
                const int trow = t0 + wm * 64 + m * 16 + g * 4 + reg;
                ep[((size_t)(x * 2 + wn) * B_DIM + b) * T_DIM + trow] = s;
            }
        }
    }
}

// ---------------- serial fallback k_main (r12-verified, f32-h path) ----------------
__global__ void __launch_bounds__(256, 3) k_main_fb(
    const float* __restrict__ hF, const unsigned short* __restrict__ VwT,
    const unsigned short* __restrict__ GT, const unsigned short* __restrict__ P,
    const float* __restrict__ SWp, const float* __restrict__ ww,
    float* __restrict__ ep) {
    __shared__ __align__(16) float AsF[8192];
    __shared__ unsigned short Bs[128 * 64];
    unsigned short* As2 = (unsigned short*)AsF;

    const int bid = blockIdx.x;
    const int wg  = (bid & 7) * 128 + (bid >> 3);
    const int x = wg & 3, yy = wg >> 2;
    const int w0 = x * 128;
    const int b  = yy >> 3;
    const int t0 = (yy & 7) * 128;

    const int tid  = threadIdx.x;
    const int lane = tid & 63;
    const int wv   = tid >> 6;
    const int wm = wv >> 1, wn = wv & 1;
    const int g = lane >> 4, r16 = lane & 15;
    const int s7 = r16 & 7;

    f32x4 acc[4][4];
#pragma unroll
    for (int m = 0; m < 4; ++m)
#pragma unroll
        for (int n = 0; n < 4; ++n) acc[m][n] = (f32x4)0.f;

    const int kstart = max(0, t0 - 512);
    const int kend   = min(T_DIM - 1, t0 + 639);
    const int NS2    = (kend - kstart + 1) >> 6;

    const int rB = lane >> 3;
    const int cB = ((lane & 7) ^ rB) * 8;
    const float* hS[8];
    {
        const int rl = lane >> 4, cl = lane & 15;
#pragma unroll
        for (int q = 0; q < 8; ++q) {
            const int row = wv * 32 + q * 4 + rl;
            hS[q] = hF + ((size_t)(t0 + row) * B_DIM + b) * DIMH + ((cl ^ (row & 7)) << 2);
        }
    }
    const unsigned short* vS[4];
    const unsigned short* gS[4];
#pragma unroll
    for (int q = 0; q < 4; ++q) {
        vS[q] = VwT + (size_t)(w0 + wv * 32 + q * 8 + rB) * DIMH + cB;
        gS[q] = GT  + (size_t)(w0 + wv * 32 + q * 8 + rB) * T_DIM + kstart + cB;
    }
    const unsigned short* Pb = P + (size_t)b * 8 * 2048;
    const unsigned short* pS[4];
#pragma unroll
    for (int q = 0; q < 4; ++q) {
        const int row = wv * 32 + q * 8 + rB;
        const int jb = kstart + ((lane & 7) ^ rB) * 8 + 1024 - (t0 + row);
        const int sj = jb & 7;
        pS[q] = Pb + sj * 2048 + (jb - sj);
    }
    const bool zrow = (t0 + wm * 64 + r16 == 0);

    for (int k0 = 0; k0 < DIMH; k0 += 64) {
        __syncthreads();
#pragma unroll
        for (int q = 0; q < 8; ++q) gl16f(hS[q] + k0, AsF + (wv * 32 + q * 4) * 64);
#pragma unroll
        for (int q = 0; q < 4; ++q) gl16(vS[q] + k0, Bs + (wv * 32 + q * 8) * 64);
        __syncthreads();
#pragma unroll
        for (int ks = 0; ks < 2; ++ks) {
            short8 af[4], bf[4];
#pragma unroll
            for (int m = 0; m < 4; ++m) {
                const int base = (wm * 64 + m * 16 + r16) * 64;
                const int clo = ((ks * 8 + 2 * g) ^ s7) * 4;
                const int chi = ((ks * 8 + 2 * g + 1) ^ s7) * 4;
                af[m] = pack8(*(const float4*)&AsF[base + clo],
                              *(const float4*)&AsF[base + chi]);
            }
#pragma unroll
            for (int n = 0; n < 4; ++n)
                bf[n] = *(const short8*)&Bs[(wn * 64 + n * 16 + r16) * 64 +
                                            ((ks * 4 + g) ^ s7) * 8];
#pragma unroll
            for (int m = 0; m < 4; ++m)
#pragma unroll
                for (int n = 0; n < 4; ++n)
                    acc[m][n] = __builtin_amdgcn_mfma_f32_16x16x32_bf16(
                        af[m], bf[n], acc[m][n], 0, 0, 0);
        }
    }
    for (int s2 = 0; s2 < NS2; ++s2) {
        const int o = s2 * 64;
        __syncthreads();
#pragma unroll
        for (int q = 0; q < 4; ++q) gl16(pS[q] + o, As2 + (wv * 32 + q * 8) * 64);
#pragma unroll
        for (int q = 0; q < 4; ++q) gl16(gS[q] + o, Bs + (wv * 32 + q * 8) * 64);
        __syncthreads();
#pragma unroll
        for (int ks = 0; ks < 2; ++ks) {
            short8 af[4], bf[4];
#pragma unroll
            for (int m = 0; m < 4; ++m)
                af[m] = *(const short8*)&As2[(wm * 64 + m * 16 + r16) * 64 +
                                             ((ks * 4 + g) ^ s7) * 8];
            if (zrow) af[0] = (short8)(short)0;
#pragma unroll
            for (int n = 0; n < 4; ++n)
                bf[n] = *(const short8*)&Bs[(wn * 64 + n * 16 + r16) * 64 +
                                            ((ks * 4 + g) ^ s7) * 8];
#pragma unroll
            for (int m = 0; m < 4; ++m)
#pragma unroll
                for (int n = 0; n < 4; ++n)
                    acc[m][n] = __builtin_amdgcn_mfma_f32_16x16x32_bf16(
                        af[m], bf[n], acc[m][n], 0, 0, 0);
        }
    }
    float swv[4], wwv[4];
#pragma unroll
    for (int n = 0; n < 4; ++n) {
        const int w = w0 + wn * 64 + n * 16 + r16;
        float sv = 0.f;
#pragma unroll
        for (int q = 0; q < 4; ++q)
            sv += SWp[((size_t)q * B_DIM + b) * DIMW + w];
        swv[n] = sv;
        wwv[n] = ww[w];
    }
#pragma unroll
    for (int m = 0; m < 4; ++m) {
#pragma unroll
        for (int reg = 0; reg < 4; ++reg) {
            float s = 0.f;
#pragma unroll
            for (int n = 0; n < 4; ++n)
                s = fmaf(fast_tanh(acc[m][n][reg] + swv[n]), wwv[n], s);
            s += __shfl_xor(s, 1, 64);
            s += __shfl_xor(s, 2, 64);
            s += __shfl_xor(s, 4, 64);
            s += __shfl_xor(s, 8, 64);
            if (r16 == 0) {
                const int trow = t0 + wm * 64 + m * 16 + g * 4 + reg;
                ep[((size_t)(x * 2 + wn) * B_DIM + b) * T_DIM + trow] = s;
            }
        }
    }
}

// ---------------- softmax over t per batch (sums 8 e-partials, r12-verified) ----------------
__device__ __forceinline__ float decode_beta(const void* p) {
    const int iv = *(const int*)p;
    const float fv = __int_as_float(iv);
    const float afv = fabsf(fv);
    if (afv >= 1e-6f && afv <= 1e6f) return fv;
    return (float)iv;
}

__global__ void k_softmax(const float* __restrict__ ep, const void* __restrict__ beta_p,
                          float* __restrict__ out) {
    const int b = blockIdx.x;
    const float beta = decode_beta(beta_p);
    __shared__ float redm[4];
    __shared__ float reds[4];
    float v[4];
    float m = -INFINITY;
#pragma unroll
    for (int i = 0; i < 4; ++i) {
        const int t = threadIdx.x * 4 + i;
        float ev = 0.f;
#pragma unroll
        for (int xq = 0; xq < 8; ++xq)
            ev += ep[((size_t)xq * B_DIM + b) * T_DIM + t];
        v[i] = beta * ev;
        m = fmaxf(m, v[i]);
    }
    for (int off = 1; off < 64; off <<= 1) m = fmaxf(m, __shfl_xor(m, off, 64));
    const int wid = threadIdx.x >> 6, lane = threadIdx.x & 63;
    if (lane == 0) redm[wid] = m;
    __syncthreads();
    m = fmaxf(fmaxf(redm[0], redm[1]), fmaxf(redm[2], redm[3]));
    float s = 0.f;
    float ex[4];
#pragma unroll
    for (int i = 0; i < 4; ++i) { ex[i] = expf(v[i] - m); s += ex[i]; }
    for (int off = 1; off < 64; off <<= 1) s += __shfl_xor(s, off, 64);
    if (lane == 0) reds[wid] = s;
    __syncthreads();
    s = reds[0] + reds[1] + reds[2] + reds[3];
    const float inv = 1.f / s;
#pragma unroll
    for (int i = 0; i < 4; ++i)
        out[(size_t)b * T_DIM + threadIdx.x * 4 + i] = ex[i] * inv;
}

extern "C" void kernel_launch(void* const* d_in, const int* in_sizes, int n_in,
                              void* d_out, int out_size, void* d_ws, size_t ws_size,
                              hipStream_t stream) {
    const float* F      = (const float*)d_in[0];
    const float* a_prev = (const float*)d_in[1];
    const float* s_prev = (const float*)d_in[2];
    const float* h      = (const float*)d_in[3];
    const float* Ww     = (const float*)d_in[4];
    const float* Vw     = (const float*)d_in[5];
    const float* Vb     = (const float*)d_in[6];
    const float* Uw     = (const float*)d_in[7];
    const float* ww     = (const float*)d_in[8];
    const void*  beta_p = d_in[9];
    float* out = (float*)d_out;

    char* ws = (char*)d_ws;
    unsigned short* GT  = (unsigned short*)(ws);                              // 1 MB
    unsigned short* VwT = (unsigned short*)(ws + (1u << 20));                 // 512 KB
    unsigned short* P   = (unsigned short*)(ws + (1u << 20) + (512u << 10));  // 1 MB
    float* SWp = (float*)(ws + (2u << 20) + (512u << 10));                    // 256 KB
    float* ep  = (float*)(ws + (2u << 20) + (768u << 10));                    // 1 MB (8 partials)
    unsigned short* hB = (unsigned short*)(ws + (4u << 20));                  // 32 MB if available

    const bool big = ws_size >= (36ull << 20);
    const int nPack = big ? 1024 : 0;

    k_prep_all<<<dim3(nPack + 1088), 256, 0, stream>>>(
        F, Uw, Vw, a_prev, s_prev, Ww, Vb, h, GT, VwT, P, SWp, hB, nPack);
    if (big) {
        k_main_pipe<<<dim3(1024), 256, 0, stream>>>(hB, VwT, GT, P, SWp, ww, ep);
    } else {
        k_main_fb<<<dim3(1024), 256, 0, stream>>>(h, VwT, GT, P, SWp, ww, ep);
    }
    k_softmax<<<dim3(32), 256, 0, stream>>>(ep, beta_p, out);
}

// Round 15
// 106.109 us; speedup vs baseline: 1.3862x; 1.3862x over previous
//
#include <hip/hip_runtime.h>
#include <hip/hip_bf16.h>
#include <math.h>

#define T_DIM 1024
#define B_DIM 32
#define DIMF 512
#define DIMH 512
#define DIMS 1024
#define DIMW 512

typedef __attribute__((ext_vector_type(8))) short short8;
typedef __attribute__((ext_vector_type(4))) float f32x4;

__device__ __forceinline__ unsigned f2bf1(float x) {
    unsigned a = __float_as_uint(x);
    return (a + 0x7FFFu + ((a >> 16) & 1u)) >> 16;
}
__device__ __forceinline__ unsigned f2bf2(float lo, float hi) {
    return f2bf1(lo) | (f2bf1(hi) << 16);
}
__device__ __forceinline__ float fast_tanh(float x) {
    return 1.f - __fdividef(2.f, 1.f + __expf(x + x));
}
__device__ __forceinline__ unsigned short bf1(float x) {
    __hip_bfloat16 b = __float2bfloat16(x);
    return *reinterpret_cast<unsigned short*>(&b);
}
__device__ __forceinline__ short8 pack8(float4 a, float4 c) {
    union { unsigned short us[8]; short8 s; } u;
    u.us[0] = bf1(a.x); u.us[1] = bf1(a.y); u.us[2] = bf1(a.z); u.us[3] = bf1(a.w);
    u.us[4] = bf1(c.x); u.us[5] = bf1(c.y); u.us[6] = bf1(c.z); u.us[7] = bf1(c.w);
    return u.s;
}

// async global->LDS, 16B/lane; LDS dest wave-uniform, global src per-lane
__device__ __forceinline__ void gl16(const unsigned short* g, unsigned short* l) {
    __builtin_amdgcn_global_load_lds(
        (const __attribute__((address_space(1))) unsigned int*)g,
        (__attribute__((address_space(3))) unsigned int*)l, 16, 0, 0);
}
__device__ __forceinline__ void gl16f(const float* g, float* l) {
    __builtin_amdgcn_global_load_lds(
        (const __attribute__((address_space(1))) unsigned int*)g,
        (__attribute__((address_space(3))) unsigned int*)l, 16, 0, 0);
}

// ================= merged prep kernel (r12-verified) =================
__global__ void __launch_bounds__(256) k_prep_all(
    const float* __restrict__ F, const float* __restrict__ Uw,
    const float* __restrict__ Vw, const float* __restrict__ a_prev,
    const float* __restrict__ s_prev, const float* __restrict__ Ww,
    const float* __restrict__ Vb, const float* __restrict__ h,
    unsigned short* __restrict__ GT, unsigned short* __restrict__ VwT,
    unsigned short* __restrict__ P, float* __restrict__ SWp,
    unsigned short* __restrict__ hB, int nPack) {
    __shared__ float sh[8192];
    const int bz = blockIdx.x;
    const int tid = threadIdx.x;

    if (bz < nPack) {
        for (unsigned i = bz * 256 + tid; i < 32768u * 64; i += (unsigned)nPack * 256) {
            const int r = i >> 6, c8 = (i & 63) * 8;
            const int bb = r >> 10, t = r & 1023;
            const float* src = h + ((size_t)(t * 32 + bb)) * 512 + c8;
            const float4 v0 = *(const float4*)(src);
            const float4 v1 = *(const float4*)(src + 4);
            union { unsigned short us[8]; uint4 u4; } o;
            o.us[0] = bf1(v0.x); o.us[1] = bf1(v0.y);
            o.us[2] = bf1(v0.z); o.us[3] = bf1(v0.w);
            o.us[4] = bf1(v1.x); o.us[5] = bf1(v1.y);
            o.us[6] = bf1(v1.z); o.us[7] = bf1(v1.w);
            *(uint4*)(hB + (size_t)r * 512 + c8) = o.u4;
        }
        return;
    }
    const int bz2 = bz - nPack;
    if (bz2 < 512) {
        const int rt = bz2 & 63, ct = bz2 >> 6;
        const int r0g = rt * 16;
        const float4* Fv = (const float4*)(F + (size_t)r0g * DIMF);
        float4* shv = (float4*)sh;
        for (int i = tid; i < 16 * DIMF / 4; i += 256) shv[i] = Fv[i];
        __syncthreads();
        const int c = ct * 64 + (tid & 63);
        const int r0 = (tid >> 6) * 4;
        float acc[4] = {0.f, 0.f, 0.f, 0.f};
        for (int k = 0; k < DIMF; ++k) {
            const float bv = Uw[(size_t)k * DIMW + c];
#pragma unroll
            for (int j = 0; j < 4; ++j)
                acc[j] = fmaf(sh[(r0 + j) * DIMF + k], bv, acc[j]);
        }
        uint2 o;
        o.x = f2bf2(acc[0], acc[1]);
        o.y = f2bf2(acc[2], acc[3]);
        *(uint2*)(GT + (size_t)c * T_DIM + r0g + r0) = o;
        return;
    }
    const int bz3 = bz2 - 512;
    if (bz3 < 512) {
        if (bz3 < 256) {
            const int k0 = (bz3 >> 4) * 32, n0 = (bz3 & 15) * 32;
            const int x = tid & 31, y = tid >> 5;
#pragma unroll
            for (int i = 0; i < 4; ++i)
                sh[(y + 8 * i) * 33 + x] = Vw[(size_t)(k0 + y + 8 * i) * DIMW + n0 + x];
            __syncthreads();
#pragma unroll
            for (int i = 0; i < 4; ++i) {
                const int n = n0 + y + 8 * i;
                VwT[(size_t)n * DIMH + k0 + x] = (unsigned short)f2bf1(sh[x * 33 + y + 8 * i]);
            }
        } else {
            const int bs = bz3 - 256;
            const int b = bs >> 3, s = bs & 7;
            for (int i = tid; i < 2048; i += 256) {
                const int j = i + s;
                float v = 0.f;
                if (j >= 512 && j < 1536) v = a_prev[(size_t)b * T_DIM + j - 512];
                P[(size_t)bs * 2048 + i] = (unsigned short)f2bf1(v);
            }
        }
        return;
    }
    {
        const int bz4 = bz3 - 512;
        const int c0 = (bz4 & 15) * 32, q = bz4 >> 4;
        float (*shb)[256] = (float(*)[256])sh;
        for (int i = tid; i < 32 * 64; i += 256) {
            const int r = i >> 6, c4 = (i & 63) * 4;
            *(float4*)&shb[r][c4] = *(const float4*)(s_prev + (size_t)r * DIMS + q * 256 + c4);
        }
        __syncthreads();
        const int c  = c0 + (tid & 31);
        const int bg = tid >> 5;
        float acc[4];
#pragma unroll
        for (int j = 0; j < 4; ++j) acc[j] = (q == 0) ? Vb[c] : 0.f;
        const float* W = Ww + (size_t)q * 256 * DIMW;
        for (int k = 0; k < 256; ++k) {
            const float w = W[(size_t)k * DIMW + c];
#pragma unroll
            for (int j = 0; j < 4; ++j)
                acc[j] = fmaf(shb[bg + 8 * j][k], w, acc[j]);
        }
#pragma unroll
        for (int j = 0; j < 4; ++j)
            SWp[((size_t)q * B_DIM + bg + 8 * j) * DIMW + c] = acc[j];
    }
}

// ======== k_main dbuf: stage(u+1) || compute(u), ONE __syncthreads per step, no asm ========
// grid 1024 (XCD-swizzled), 256 threads (4 waves 2x2), tile 128x128, BK=64
__global__ void __launch_bounds__(256) k_main_db(
    const unsigned short* __restrict__ hB, const unsigned short* __restrict__ VwT,
    const unsigned short* __restrict__ GT, const unsigned short* __restrict__ P,
    const float* __restrict__ SWp, const float* __restrict__ ww,
    float* __restrict__ ep) {
    __shared__ unsigned short As2[2][8192];   // 2 x 16 KB
    __shared__ unsigned short Bs[2][8192];    // 2 x 16 KB

    const int bid = blockIdx.x;
    const int wg  = (bid & 7) * 128 + (bid >> 3);   // bijective: 1024 % 8 == 0
    const int x = wg & 3, yy = wg >> 2;
    const int w0 = x * 128;
    const int b  = yy >> 3;
    const int t0 = (yy & 7) * 128;

    const int tid  = threadIdx.x;
    const int lane = tid & 63;
    const int wv   = tid >> 6;
    const int wm = wv >> 1, wn = wv & 1;
    const int g = lane >> 4, r16 = lane & 15;
    const int s7 = r16 & 7;

    f32x4 acc[4][4];
#pragma unroll
    for (int m = 0; m < 4; ++m)
#pragma unroll
        for (int n = 0; n < 4; ++n) acc[m][n] = (f32x4)0.f;

    const int kstart = max(0, t0 - 512);
    const int kend   = min(T_DIM - 1, t0 + 639);
    const int NS2    = (kend - kstart + 1) >> 6;    // 10..16 steps of K=64
    const int NT     = 8 + NS2;                     // 18..24

    // ---- staging sources (r12-verified pre-swizzle): 8 rows/gl16 ----
    const int rB = lane >> 3;                       // row-in-8 (= row&7)
    const int cB = ((lane & 7) ^ rB) * 8;
    const unsigned short* hSb[4];
    const unsigned short* vS[4];
    const unsigned short* gS[4];
#pragma unroll
    for (int q = 0; q < 4; ++q) {
        hSb[q] = hB + ((size_t)(b * 1024 + t0 + wv * 32 + q * 8 + rB)) * 512 + cB;
        vS[q]  = VwT + (size_t)(w0 + wv * 32 + q * 8 + rB) * DIMH + cB;
        gS[q]  = GT  + (size_t)(w0 + wv * 32 + q * 8 + rB) * T_DIM + kstart + cB;
    }
    const unsigned short* Pb = P + (size_t)b * 8 * 2048;
    const unsigned short* pS[4];
#pragma unroll
    for (int q = 0; q < 4; ++q) {
        const int row = wv * 32 + q * 8 + rB;
        const int jb = kstart + ((lane & 7) ^ rB) * 8 + 1024 - (t0 + row);  // in [385,1087]
        const int sj = jb & 7;
        pS[q] = Pb + sj * 2048 + (jb - sj);
    }
    const bool zrow = (t0 + wm * 64 + r16 == 0);

    // unified stage: step u (u<8: part1 from hB/VwT; else part2 from P/GT)
#define STAGE(u, j)                                                          \
    {                                                                        \
        if ((u) < 8) {                                                       \
            const int o_ = (u) * 64;                                         \
            _Pragma("unroll")                                                \
            for (int q = 0; q < 4; ++q) {                                    \
                gl16(hSb[q] + o_, &As2[j][(wv * 32 + q * 8) * 64]);          \
                gl16(vS[q] + o_,  &Bs[j][(wv * 32 + q * 8) * 64]);           \
            }                                                                \
        } else {                                                             \
            const int o_ = ((u) - 8) * 64;                                   \
            _Pragma("unroll")                                                \
            for (int q = 0; q < 4; ++q) {                                    \
                gl16(pS[q] + o_, &As2[j][(wv * 32 + q * 8) * 64]);           \
                gl16(gS[q] + o_, &Bs[j][(wv * 32 + q * 8) * 64]);            \
            }                                                                \
        }                                                                    \
    }

    // ---- prologue: stage step 0 into buf 0 ----
    STAGE(0, 0);
    __syncthreads();   // compiler drains vmcnt(0) before s_barrier

    for (int u = 0; u < NT; ++u) {
        const int cur = u & 1;
        if (u + 1 < NT) STAGE(u + 1, cur ^ 1);   // issue next-step loads first
        const bool p2z = (u >= 8) && zrow;
#pragma unroll
        for (int ks = 0; ks < 2; ++ks) {
            short8 af[4], bf[4];
#pragma unroll
            for (int m = 0; m < 4; ++m)
                af[m] = *(const short8*)&As2[cur][(wm * 64 + m * 16 + r16) * 64 +
                                                  ((ks * 4 + g) ^ s7) * 8];
            if (p2z) af[0] = (short8)(short)0;   // f row t=0 is zero (part2 only)
#pragma unroll
            for (int n = 0; n < 4; ++n)
                bf[n] = *(const short8*)&Bs[cur][(wn * 64 + n * 16 + r16) * 64 +
                                                 ((ks * 4 + g) ^ s7) * 8];
#pragma unroll
            for (int m = 0; m < 4; ++m)
#pragma unroll
                for (int n = 0; n < 4; ++n)
                    acc[m][n] = __builtin_amdgcn_mfma_f32_16x16x32_bf16(
                        af[m], bf[n], acc[m][n], 0, 0, 0);
        }
        __syncthreads();   // drains this step's stage; releases buf for overwrite
    }
#undef STAGE

    // ---- epilogue (r12-verified) ----
    float swv[4], wwv[4];
#pragma unroll
    for (int n = 0; n < 4; ++n) {
        const int w = w0 + wn * 64 + n * 16 + r16;
        float sv = 0.f;
#pragma unroll
        for (int q = 0; q < 4; ++q)
            sv += SWp[((size_t)q * B_DIM + b) * DIMW + w];
        swv[n] = sv;
        wwv[n] = ww[w];
    }
#pragma unroll
    for (int m = 0; m < 4; ++m) {
#pragma unroll
        for (int reg = 0; reg < 4; ++reg) {
            float s = 0.f;
#pragma unroll
            for (int n = 0; n < 4; ++n)
                s = fmaf(fast_tanh(acc[m][n][reg] + swv[n]), wwv[n], s);
            s += __shfl_xor(s, 1, 64);
            s += __shfl_xor(s, 2, 64);
            s += __shfl_xor(s, 4, 64);
            s += __shfl_xor(s, 8, 64);
            if (r16 == 0) {
                const int trow = t0 + wm * 64 + m * 16 + g * 4 + reg;
                ep[((size_t)(x * 2 + wn) * B_DIM + b) * T_DIM + trow] = s;
            }
        }
    }
}

// ---------------- serial fallback k_main (r12-verified, f32-h path) ----------------
__global__ void __launch_bounds__(256, 3) k_main_fb(
    const float* __restrict__ hF, const unsigned short* __restrict__ VwT,
    const unsigned short* __restrict__ GT, const unsigned short* __restrict__ P,
    const float* __restrict__ SWp, const float* __restrict__ ww,
    float* __restrict__ ep) {
    __shared__ __align__(16) float AsF[8192];
    __shared__ unsigned short Bs[128 * 64];
    unsigned short* As2 = (unsigned short*)AsF;

    const int bid = blockIdx.x;
    const int wg  = (bid & 7) * 128 + (bid >> 3);
    const int x = wg & 3, yy = wg >> 2;
    const int w0 = x * 128;
    const int b  = yy >> 3;
    const int t0 = (yy & 7) * 128;

    const int tid  = threadIdx.x;
    const int lane = tid & 63;
    const int wv   = tid >> 6;
    const int wm = wv >> 1, wn = wv & 1;
    const int g = lane >> 4, r16 = lane & 15;
    const int s7 = r16 & 7;

    f32x4 acc[4][4];
#pragma unroll
    for (int m = 0; m < 4; ++m)
#pragma unroll
        for (int n = 0; n < 4; ++n) acc[m][n] = (f32x4)0.f;

    const int kstart = max(0, t0 - 512);
    const int kend   = min(T_DIM - 1, t0 + 639);
    const int NS2    = (kend - kstart + 1) >> 6;

    const int rB = lane >> 3;
    const int cB = ((lane & 7) ^ rB) * 8;
    const float* hS[8];
    {
        const int rl = lane >> 4, cl = lane & 15;
#pragma unroll
        for (int q = 0; q < 8; ++q) {
            const int row = wv * 32 + q * 4 + rl;
            hS[q] = hF + ((size_t)(t0 + row) * B_DIM + b) * DIMH + ((cl ^ (row & 7)) << 2);
        }
    }
    const unsigned short* vS[4];
    const unsigned short* gS[4];
#pragma unroll
    for (int q = 0; q < 4; ++q) {
        vS[q] = VwT + (size_t)(w0 + wv * 32 + q * 8 + rB) * DIMH + cB;
        gS[q] = GT  + (size_t)(w0 + wv * 32 + q * 8 + rB) * T_DIM + kstart + cB;
    }
    const unsigned short* Pb = P + (size_t)b * 8 * 2048;
    const unsigned short* pS[4];
#pragma unroll
    for (int q = 0; q < 4; ++q) {
        const int row = wv * 32 + q * 8 + rB;
        const int jb = kstart + ((lane & 7) ^ rB) * 8 + 1024 - (t0 + row);
        const int sj = jb & 7;
        pS[q] = Pb + sj * 2048 + (jb - sj);
    }
    const bool zrow = (t0 + wm * 64 + r16 == 0);

    for (int k0 = 0; k0 < DIMH; k0 += 64) {
        __syncthreads();
#pragma unroll
        for (int q = 0; q < 8; ++q) gl16f(hS[q] + k0, AsF + (wv * 32 + q * 4) * 64);
#pragma unroll
        for (int q = 0; q < 4; ++q) gl16(vS[q] + k0, Bs + (wv * 32 + q * 8) * 64);
        __syncthreads();
#pragma unroll
        for (int ks = 0; ks < 2; ++ks) {
            short8 af[4], bf[4];
#pragma unroll
            for (int m = 0; m < 4; ++m) {
                const int base = (wm * 64 + m * 16 + r16) * 64;
                const int clo = ((ks * 8 + 2 * g) ^ s7) * 4;
                const int chi = ((ks * 8 + 2 * g + 1) ^ s7) * 4;
                af[m] = pack8(*(const float4*)&AsF[base + clo],
                              *(const float4*)&AsF[base + chi]);
            }
#pragma unroll
            for (int n = 0; n < 4; ++n)
                bf[n] = *(const short8*)&Bs[(wn * 64 + n * 16 + r16) * 64 +
                                            ((ks * 4 + g) ^ s7) * 8];
#pragma unroll
            for (int m = 0; m < 4; ++m)
#pragma unroll
                for (int n = 0; n < 4; ++n)
                    acc[m][n] = __builtin_amdgcn_mfma_f32_16x16x32_bf16(
                        af[m], bf[n], acc[m][n], 0, 0, 0);
        }
    }
    for (int s2 = 0; s2 < NS2; ++s2) {
        const int o = s2 * 64;
        __syncthreads();
#pragma unroll
        for (int q = 0; q < 4; ++q) gl16(pS[q] + o, As2 + (wv * 32 + q * 8) * 64);
#pragma unroll
        for (int q = 0; q < 4; ++q) gl16(gS[q] + o, Bs + (wv * 32 + q * 8) * 64);
        __syncthreads();
#pragma unroll
        for (int ks = 0; ks < 2; ++ks) {
            short8 af[4], bf[4];
#pragma unroll
            for (int m = 0; m < 4; ++m)
                af[m] = *(const short8*)&As2[(wm * 64 + m * 16 + r16) * 64 +
                                             ((ks * 4 + g) ^ s7) * 8];
            if (zrow) af[0] = (short8)(short)0;
#pragma unroll
            for (int n = 0; n < 4; ++n)
                bf[n] = *(const short8*)&Bs[(wn * 64 + n * 16 + r16) * 64 +
                                            ((ks * 4 + g) ^ s7) * 8];
#pragma unroll
            for (int m = 0; m < 4; ++m)
#pragma unroll
                for (int n = 0; n < 4; ++n)
                    acc[m][n] = __builtin_amdgcn_mfma_f32_16x16x32_bf16(
                        af[m], bf[n], acc[m][n], 0, 0, 0);
        }
    }
    float swv[4], wwv[4];
#pragma unroll
    for (int n = 0; n < 4; ++n) {
        const int w = w0 + wn * 64 + n * 16 + r16;
        float sv = 0.f;
#pragma unroll
        for (int q = 0; q < 4; ++q)
            sv += SWp[((size_t)q * B_DIM + b) * DIMW + w];
        swv[n] = sv;
        wwv[n] = ww[w];
    }
#pragma unroll
    for (int m = 0; m < 4; ++m) {
#pragma unroll
        for (int reg = 0; reg < 4; ++reg) {
            float s = 0.f;
#pragma unroll
            for (int n = 0; n < 4; ++n)
                s = fmaf(fast_tanh(acc[m][n][reg] + swv[n]), wwv[n], s);
            s += __shfl_xor(s, 1, 64);
            s += __shfl_xor(s, 2, 64);
            s += __shfl_xor(s, 4, 64);
            s += __shfl_xor(s, 8, 64);
            if (r16 == 0) {
                const int trow = t0 + wm * 64 + m * 16 + g * 4 + reg;
                ep[((size_t)(x * 2 + wn) * B_DIM + b) * T_DIM + trow] = s;
            }
        }
    }
}

// ---------------- softmax over t per batch (sums 8 e-partials, r12-verified) ----------------
__device__ __forceinline__ float decode_beta(const void* p) {
    const int iv = *(const int*)p;
    const float fv = __int_as_float(iv);
    const float afv = fabsf(fv);
    if (afv >= 1e-6f && afv <= 1e6f) return fv;
    return (float)iv;
}

__global__ void k_softmax(const float* __restrict__ ep, const void* __restrict__ beta_p,
                          float* __restrict__ out) {
    const int b = blockIdx.x;
    const float beta = decode_beta(beta_p);
    __shared__ float redm[4];
    __shared__ float reds[4];
    float v[4];
    float m = -INFINITY;
#pragma unroll
    for (int i = 0; i < 4; ++i) {
        const int t = threadIdx.x * 4 + i;
        float ev = 0.f;
#pragma unroll
        for (int xq = 0; xq < 8; ++xq)
            ev += ep[((size_t)xq * B_DIM + b) * T_DIM + t];
        v[i] = beta * ev;
        m = fmaxf(m, v[i]);
    }
    for (int off = 1; off < 64; off <<= 1) m = fmaxf(m, __shfl_xor(m, off, 64));
    const int wid = threadIdx.x >> 6, lane = threadIdx.x & 63;
    if (lane == 0) redm[wid] = m;
    __syncthreads();
    m = fmaxf(fmaxf(redm[0], redm[1]), fmaxf(redm[2], redm[3]));
    float s = 0.f;
    float ex[4];
#pragma unroll
    for (int i = 0; i < 4; ++i) { ex[i] = expf(v[i] - m); s += ex[i]; }
    for (int off = 1; off < 64; off <<= 1) s += __shfl_xor(s, off, 64);
    if (lane == 0) reds[wid] = s;
    __syncthreads();
    s = reds[0] + reds[1] + reds[2] + reds[3];
    const float inv = 1.f / s;
#pragma unroll
    for (int i = 0; i < 4; ++i)
        out[(size_t)b * T_DIM + threadIdx.x * 4 + i] = ex[i] * inv;
}

extern "C" void kernel_launch(void* const* d_in, const int* in_sizes, int n_in,
                              void* d_out, int out_size, void* d_ws, size_t ws_size,
                              hipStream_t stream) {
    const float* F      = (const float*)d_in[0];
    const float* a_prev = (const float*)d_in[1];
    const float* s_prev = (const float*)d_in[2];
    const float* h      = (const float*)d_in[3];
    const float* Ww     = (const float*)d_in[4];
    const float* Vw     = (const float*)d_in[5];
    const float* Vb     = (const float*)d_in[6];
    const float* Uw     = (const float*)d_in[7];
    const float* ww     = (const float*)d_in[8];
    const void*  beta_p = d_in[9];
    float* out = (float*)d_out;

    char* ws = (char*)d_ws;
    unsigned short* GT  = (unsigned short*)(ws);                              // 1 MB
    unsigned short* VwT = (unsigned short*)(ws + (1u << 20));                 // 512 KB
    unsigned short* P   = (unsigned short*)(ws + (1u << 20) + (512u << 10));  // 1 MB
    float* SWp = (float*)(ws + (2u << 20) + (512u << 10));                    // 256 KB
    float* ep  = (float*)(ws + (2u << 20) + (768u << 10));                    // 1 MB (8 partials)
    unsigned short* hB = (unsigned short*)(ws + (4u << 20));                  // 32 MB if available

    const bool big = ws_size >= (36ull << 20);
    const int nPack = big ? 1024 : 0;

    k_prep_all<<<dim3(nPack + 1088), 256, 0, stream>>>(
        F, Uw, Vw, a_prev, s_prev, Ww, Vb, h, GT, VwT, P, SWp, hB, nPack);
    if (big) {
        k_main_db<<<dim3(1024), 256, 0, stream>>>(hB, VwT, GT, P, SWp, ww, ep);
    } else {
        k_main_fb<<<dim3(1024), 256, 0, stream>>>(h, VwT, GT, P, SWp, ww, ep);
    }
    k_softmax<<<dim3(32), 256, 0, stream>>>(ep, beta_p, out);
}